// Round 6
// baseline (189.379 us; speedup 1.0000x reference)
//
#include <hip/hip_runtime.h>

typedef unsigned short u16;
typedef unsigned int u32;
typedef __attribute__((ext_vector_type(8))) short s16x8;   // 8 bf16 (4 VGPRs) MFMA A/B frag
typedef __attribute__((ext_vector_type(4))) float f32x4;   // MFMA C/D frag

#define DIM    1024
#define NHEADS 16
#define HD     64
#define NSEQ   2048
#define QKVN   3072

__device__ __forceinline__ u16 f2bf(float f) {
  u32 u = __float_as_uint(f);
  u += 0x7FFF + ((u >> 16) & 1);   // RNE
  return (u16)(u >> 16);
}

// raw v_exp_f32 (exp2). HIP's exp2f() is precise libm (~10 ops) — r3 regression.
__device__ __forceinline__ float vexp2(float x) {
  float r;
  asm volatile("v_exp_f32 %0, %1" : "=v"(r) : "v"(x));
  return r;
}

// async global->LDS, 16B per lane. LDS dst = wave-uniform base + lane*16.
__device__ __forceinline__ void async16(const u16* g, u16* l) {
  __builtin_amdgcn_global_load_lds(
      (const __attribute__((address_space(1))) unsigned int*)g,
      (__attribute__((address_space(3))) unsigned int*)l, 16, 0, 0);
}

// ---------------------------------------------------------------- cast fp32 -> bf16
__global__ void cast_all(const float* __restrict__ x, const float* __restrict__ wq,
                         const float* __restrict__ wp, u16* __restrict__ xo,
                         u16* __restrict__ wqo, u16* __restrict__ wpo) {
  int i = blockIdx.x * 256 + threadIdx.x;        // 2,097,152 threads, 4 floats each
  const float4* src; u16* dst; int off;
  if (i < 1048576)      { src = (const float4*)x;  dst = xo;  off = i; }
  else if (i < 1835008) { src = (const float4*)wq; dst = wqo; off = i - 1048576; }
  else                  { src = (const float4*)wp; dst = wpo; off = i - 1835008; }
  float4 f = src[off];
  ushort4 o;
  o.x = f2bf(f.x); o.y = f2bf(f.y); o.z = f2bf(f.z); o.w = f2bf(f.w);
  ((ushort4*)dst)[off] = o;
}

// ---------------------------------------------------------------- GEMM  C = A * B^T
// r3 structure (known-good): A [M,1024] bf16 K-major, B [N,1024] bf16 K-major.
// BK=64, async staging with XOR chunk swizzle c' = c ^ (row&7). 256 thr / 4 waves.
// FINAL=false: BM=128, grid 32x24; scalar coalesced Q,K stores -> qkv,
//              packed ushort4 V stores -> vt. FINAL=true: BM=64; out = C + bias.
template <bool FINAL>
__global__ __launch_bounds__(256, 3) void gemm_bt(
    const u16* __restrict__ A, const u16* __restrict__ Bw, u16* __restrict__ qkv,
    u16* __restrict__ vt, const float* __restrict__ bias, float* __restrict__ outp) {
  constexpr int K = 1024;
  constexpr int BM = FINAL ? 64 : 128;
  constexpr int MT = FINAL ? 64 : 32;
  constexpr int IT = FINAL ? 2 : 4;           // 16-row i-tiles per wave
  constexpr int ACALLS = BM / 8;              // wave-calls to stage A tile
  constexpr int TCALLS = ACALLS + 16;
  constexpr int PW = TCALLS / 4;              // calls per wave
  const int bm = blockIdx.x % MT;
  const int bn = blockIdx.x / MT;
  const int tid = threadIdx.x;
  const int wave = tid >> 6, lane = tid & 63;
  const int q4 = lane >> 4, l15 = lane & 15;
  const int wm = wave >> 1, wn = wave & 1;
  const int m0 = bm * BM, n0 = bn * 128;

  __shared__ alignas(16) u16 lsA[BM * 64];
  __shared__ alignas(16) u16 lsB[128 * 64];

  f32x4 acc[IT][4];
#pragma unroll
  for (int i = 0; i < IT; i++)
#pragma unroll
    for (int j = 0; j < 4; j++) acc[i][j] = (f32x4){0.f, 0.f, 0.f, 0.f};

  for (int k0 = 0; k0 < K; k0 += 64) {
    __syncthreads();
#pragma unroll
    for (int j = 0; j < PW; ++j) {
      int t = wave * PW + j;
      if (t < ACALLS) {
        int lin = t * 64 + lane;
        int r = lin >> 3, cs = lin & 7, c = cs ^ (r & 7);
        async16(A + (size_t)(m0 + r) * K + k0 + c * 8, lsA + t * 512);
      } else {
        int tb = t - ACALLS;
        int lin = tb * 64 + lane;
        int r = lin >> 3, cs = lin & 7, c = cs ^ (r & 7);
        async16(Bw + (size_t)(n0 + r) * K + k0 + c * 8, lsB + tb * 512);
      }
    }
    __syncthreads();
#pragma unroll
    for (int kc = 0; kc < 2; ++kc) {
      s16x8 af[IT], bfr[4];
#pragma unroll
      for (int i = 0; i < IT; ++i) {
        int r = wm * (IT * 16) + i * 16 + l15;
        int c = (kc * 4 + q4) ^ (r & 7);
        af[i] = *(const s16x8*)(lsA + r * 64 + c * 8);
      }
#pragma unroll
      for (int j = 0; j < 4; ++j) {
        int r = wn * 64 + j * 16 + l15;
        int c = (kc * 4 + q4) ^ (r & 7);
        bfr[j] = *(const s16x8*)(lsB + r * 64 + c * 8);
      }
#pragma unroll
      for (int i = 0; i < IT; ++i)
#pragma unroll
        for (int j = 0; j < 4; ++j)
          acc[i][j] = __builtin_amdgcn_mfma_f32_16x16x32_bf16(af[i], bfr[j], acc[i][j], 0, 0, 0);
    }
  }

  // epilogue: C/D layout col=lane&15, row=quad*4+reg
#pragma unroll
  for (int i = 0; i < IT; i++) {
#pragma unroll
    for (int j = 0; j < 4; j++) {
      int n = n0 + wn * 64 + j * 16 + l15;
      int mb = m0 + wm * (IT * 16) + i * 16 + q4 * 4;
      if (FINAL) {
#pragma unroll
        for (int r = 0; r < 4; r++)
          outp[(size_t)(mb + r) * DIM + n] = acc[i][j][r] + bias[n];
      } else if (n < 2048) {
#pragma unroll
        for (int r = 0; r < 4; r++)
          qkv[(size_t)(mb + r) * QKVN + n] = f2bf(acc[i][j][r]);
      } else {
        int b = mb >> 11, tok = mb & 2047;
        int h = (n >> 6) & 15, hd = n & 63;
        ushort4 pk;
        pk.x = f2bf(acc[i][j][0]); pk.y = f2bf(acc[i][j][1]);
        pk.z = f2bf(acc[i][j][2]); pk.w = f2bf(acc[i][j][3]);
        *(ushort4*)(vt + ((size_t)((b * NHEADS + h) * HD + hd)) * NSEQ + tok) = pk;
      }
    }
  }
}

// ---------------------------------------------------------------- flash attention
// 512 blocks (blk = qt*32 + bh: same-bh blocks share an XCD -> K/V in L2),
// 256 thr / 4 waves x 32 q-rows (128 q-rows per block). 64-key tiles,
// DOUBLE-BUFFERED staging: barrier -> issue async stage(kt+1) -> compute(kt);
// the vmcnt(0) drain at the barrier is covered by a full compute phase.
// One barrier per tile (32 total vs r5's 64). 41 KB LDS -> 2 blocks/CU.
// exp2-domain softmax (Q pre-scaled by log2(e)/8, raw v_exp_f32). P truncated
// to bf16; lsum accumulates the truncated value (normalizer consistent with
// MFMA input -> no scale bias).
__global__ __launch_bounds__(256, 2) void attn_kernel(const u16* __restrict__ qkv,
                                                      const u16* __restrict__ vt,
                                                      u16* __restrict__ aout) {
  const int blk = blockIdx.x;            // 512 = 16 qtiles * 32 bh (bh fast)
  const int bh = blk & 31, qt = blk >> 5;
  const int b = bh >> 4, h = bh & 15;
  const int tid = threadIdx.x;
  const int wave = tid >> 6, lane = tid & 63;
  const int q4 = lane >> 4, l15 = lane & 15;

  __shared__ alignas(16) u16 lsK[2][64 * 64];    // [buf][key][hd], swizzled 16B chunks
  __shared__ alignas(16) u16 lsV[2][64 * 64];    // [buf][hd][key], swizzled 16B chunks
  __shared__ alignas(16) u16 lsP[4][16 * 72];    // per-wave P [qrow][key], reused per rt

  // Q A-frags in registers, pre-scaled by log2(e)/8 (f32 mul, RNE back to bf16)
  const float QSCALE = 0.18033688011112042f;     // log2(e)/8
  s16x8 aq[2][2];
#pragma unroll
  for (int rt = 0; rt < 2; ++rt)
#pragma unroll
    for (int kc = 0; kc < 2; ++kc) {
      int row = b * NSEQ + qt * 128 + wave * 32 + rt * 16 + l15;
      uint4 d = *(const uint4*)(qkv + (size_t)row * QKVN + h * HD + kc * 32 + q4 * 8);
      u32 w[4] = {d.x, d.y, d.z, d.w};
      s16x8 f;
#pragma unroll
      for (int j = 0; j < 8; ++j) {
        u16 u = (u16)(w[j >> 1] >> ((j & 1) * 16));
        float v = __uint_as_float(((u32)u) << 16) * QSCALE;
        f[j] = (short)f2bf(v);
      }
      aq[rt][kc] = f;
    }

  f32x4 o[2][4];
  float lsum[2][4] = {{0.f, 0.f, 0.f, 0.f}, {0.f, 0.f, 0.f, 0.f}};
#pragma unroll
  for (int rt = 0; rt < 2; ++rt)
#pragma unroll
    for (int ht = 0; ht < 4; ++ht) o[rt][ht] = (f32x4){0.f, 0.f, 0.f, 0.f};

  // stage tile kt into buffer buf (8 K-calls + 8 V-calls, 2+2 per wave)
  auto stage = [&](int kt, int buf) {
#pragma unroll
    for (int j = 0; j < 2; ++j) {
      int t = wave * 2 + j;                      // 0..7
      int lin = t * 64 + lane;
      int r = lin >> 3, c = (lin & 7) ^ (r & 7);
      async16(qkv + (size_t)(b * NSEQ + kt * 64 + r) * QKVN + DIM + h * HD + c * 8,
              lsK[buf] + t * 512);
      async16(vt + (size_t)(bh * HD + r) * NSEQ + kt * 64 + c * 8,
              lsV[buf] + t * 512);
    }
  };

  stage(0, 0);

  for (int kt = 0; kt < 32; ++kt) {
    const int buf = kt & 1;
    __syncthreads();                             // stage(kt) complete; prev compute done
    if (kt + 1 < 32) stage(kt + 1, buf ^ 1);     // async into other buffer

#pragma unroll
    for (int rt = 0; rt < 2; ++rt) {
      // S = Q K^T  (16 q-rows x 64 keys)
      f32x4 s[4];
#pragma unroll
      for (int ct = 0; ct < 4; ++ct) s[ct] = (f32x4){0.f, 0.f, 0.f, 0.f};
#pragma unroll
      for (int kc = 0; kc < 2; ++kc) {
#pragma unroll
        for (int ct = 0; ct < 4; ++ct) {
          int r = ct * 16 + l15;
          int c = (kc * 4 + q4) ^ (r & 7);
          s16x8 bk = *(const s16x8*)(lsK[buf] + r * 64 + c * 8);
          s[ct] = __builtin_amdgcn_mfma_f32_16x16x32_bf16(aq[rt][kc], bk, s[ct], 0, 0, 0);
        }
      }

      // p = exp2(s) via raw v_exp_f32; truncate to bf16; lsum sums truncated value
#pragma unroll
      for (int ct = 0; ct < 4; ++ct)
#pragma unroll
        for (int r = 0; r < 4; ++r) {
          u32 u = __float_as_uint(vexp2(s[ct][r]));
          lsum[rt][r] += __uint_as_float(u & 0xffff0000u);
          lsP[wave][(q4 * 4 + r) * 72 + ct * 16 + l15] = (u16)(u >> 16);
        }

      // O += P * V  (per-wave lsP; in-order DS ops make reuse across rt safe)
#pragma unroll
      for (int kc = 0; kc < 2; ++kc) {
        s16x8 pa = *(const s16x8*)(lsP[wave] + l15 * 72 + kc * 32 + q4 * 8);
#pragma unroll
        for (int ht = 0; ht < 4; ++ht) {
          int r = ht * 16 + l15;
          int c = (kc * 4 + q4) ^ (r & 7);
          s16x8 vb = *(const s16x8*)(lsV[buf] + r * 64 + c * 8);
          o[rt][ht] = __builtin_amdgcn_mfma_f32_16x16x32_bf16(pa, vb, o[rt][ht], 0, 0, 0);
        }
      }
    }
  }

  // final row-sum reduction over the 16 l15 lanes
#pragma unroll
  for (int off = 1; off < 16; off <<= 1)
#pragma unroll
    for (int rt = 0; rt < 2; ++rt)
#pragma unroll
      for (int r = 0; r < 4; ++r) lsum[rt][r] += __shfl_xor(lsum[rt][r], off, 64);

#pragma unroll
  for (int rt = 0; rt < 2; ++rt) {
    float inv[4];
#pragma unroll
    for (int r = 0; r < 4; ++r) inv[r] = 1.0f / lsum[rt][r];
#pragma unroll
    for (int ht = 0; ht < 4; ++ht)
#pragma unroll
      for (int r = 0; r < 4; ++r) {
        int n = qt * 128 + wave * 32 + rt * 16 + q4 * 4 + r;
        int col = h * HD + ht * 16 + l15;
        aout[(size_t)(b * NSEQ + n) * DIM + col] = f2bf(o[rt][ht][r] * inv[r]);
      }
  }
}

// ---------------------------------------------------------------- launch
extern "C" void kernel_launch(void* const* d_in, const int* in_sizes, int n_in,
                              void* d_out, int out_size, void* d_ws, size_t ws_size,
                              hipStream_t stream) {
  const float* x     = (const float*)d_in[0];
  const float* w_qkv = (const float*)d_in[1];
  const float* w_prj = (const float*)d_in[2];
  const float* b_prj = (const float*)d_in[3];
  float* out = (float*)d_out;

  char* ws = (char*)d_ws;
  u16* x_bf    = (u16*)(ws);                          // 8 MB
  u16* wqkv_bf = (u16*)(ws + (size_t)(8u << 20));     // 6 MB
  u16* wprj_bf = (u16*)(ws + (size_t)(14u << 20));    // 2 MB
  u16* qkv     = (u16*)(ws + (size_t)(16u << 20));    // 24 MB (Q,K used; V slot unused)
  u16* vt      = (u16*)(ws + (size_t)(40u << 20));    // 8 MB
  u16* aout    = (u16*)(ws + (size_t)(48u << 20));    // 8 MB   total 56 MB

  cast_all<<<8192, 256, 0, stream>>>(x, w_qkv, w_prj, x_bf, wqkv_bf, wprj_bf);
  gemm_bt<false><<<32 * 24, 256, 0, stream>>>(x_bf, wqkv_bf, qkv, vt, nullptr, nullptr);
  attn_kernel<<<512, 256, 0, stream>>>(qkv, vt, aout);
  gemm_bt<true><<<64 * 8, 256, 0, stream>>>(aout, wprj_bf, nullptr, nullptr, b_prj, out);
}

// Round 7
// 187.993 us; speedup vs baseline: 1.0074x; 1.0074x over previous
//
#include <hip/hip_runtime.h>

typedef unsigned short u16;
typedef unsigned int u32;
typedef __attribute__((ext_vector_type(8))) short s16x8;   // 8 bf16 (4 VGPRs) MFMA A/B frag
typedef __attribute__((ext_vector_type(4))) short s16x4;   // 4 bf16 (2 VGPRs) 16x16x16 frag
typedef __attribute__((ext_vector_type(4))) float f32x4;   // MFMA C/D frag

#define DIM    1024
#define NHEADS 16
#define HD     64
#define NSEQ   2048
#define QKVN   3072

__device__ __forceinline__ u16 f2bf(float f) {
  u32 u = __float_as_uint(f);
  u += 0x7FFF + ((u >> 16) & 1);   // RNE
  return (u16)(u >> 16);
}

// raw v_exp_f32 (exp2). HIP's exp2f() is precise libm (~10 ops) — r3 regression.
__device__ __forceinline__ float vexp2(float x) {
  float r;
  asm volatile("v_exp_f32 %0, %1" : "=v"(r) : "v"(x));
  return r;
}

// async global->LDS, 16B per lane. LDS dst = wave-uniform base + lane*16.
__device__ __forceinline__ void async16(const u16* g, u16* l) {
  __builtin_amdgcn_global_load_lds(
      (const __attribute__((address_space(1))) unsigned int*)g,
      (__attribute__((address_space(3))) unsigned int*)l, 16, 0, 0);
}

// ---------------------------------------------------------------- cast fp32 -> bf16
__global__ void cast_all(const float* __restrict__ x, const float* __restrict__ wq,
                         const float* __restrict__ wp, u16* __restrict__ xo,
                         u16* __restrict__ wqo, u16* __restrict__ wpo) {
  int i = blockIdx.x * 256 + threadIdx.x;        // 2,097,152 threads, 4 floats each
  const float4* src; u16* dst; int off;
  if (i < 1048576)      { src = (const float4*)x;  dst = xo;  off = i; }
  else if (i < 1835008) { src = (const float4*)wq; dst = wqo; off = i - 1048576; }
  else                  { src = (const float4*)wp; dst = wpo; off = i - 1835008; }
  float4 f = src[off];
  ushort4 o;
  o.x = f2bf(f.x); o.y = f2bf(f.y); o.z = f2bf(f.z); o.w = f2bf(f.w);
  ((ushort4*)dst)[off] = o;
}

// ---------------------------------------------------------------- GEMM  C = A * B^T
// m97-exact config (HW-verified 874 TF): BK=32, LDS row stride 32 elems (64 B,
// natural 2-way bank alias = free), async16 staging, 256 thr / 4 waves.
// FINAL=false: BM=128, grid 32x24; scalar coalesced Q,K stores -> qkv,
//              packed ushort4 V stores -> vt. FINAL=true: BM=64; out = C + bias.
template <bool FINAL>
__global__ __launch_bounds__(256, 3) void gemm_bt(
    const u16* __restrict__ A, const u16* __restrict__ Bw, u16* __restrict__ qkv,
    u16* __restrict__ vt, const float* __restrict__ bias, float* __restrict__ outp) {
  constexpr int K = 1024;
  constexpr int BM = FINAL ? 64 : 128;
  constexpr int MT = FINAL ? 64 : 32;
  constexpr int IT = FINAL ? 2 : 4;           // 16-row i-tiles per wave
  constexpr int ACALLS = BM / 16;             // wave-calls to stage A tile (1 KB each)
  constexpr int TCALLS = ACALLS + 8;
  constexpr int PW = TCALLS / 4;              // calls per wave
  const int bm = blockIdx.x % MT;
  const int bn = blockIdx.x / MT;
  const int tid = threadIdx.x;
  const int wave = tid >> 6, lane = tid & 63;
  const int q4 = lane >> 4, l15 = lane & 15;
  const int wm = wave >> 1, wn = wave & 1;
  const int m0 = bm * BM, n0 = bn * 128;

  __shared__ alignas(16) u16 lsA[BM * 32];
  __shared__ alignas(16) u16 lsB[128 * 32];

  f32x4 acc[IT][4];
#pragma unroll
  for (int i = 0; i < IT; i++)
#pragma unroll
    for (int j = 0; j < 4; j++) acc[i][j] = (f32x4){0.f, 0.f, 0.f, 0.f};

  for (int k0 = 0; k0 < K; k0 += 32) {
    __syncthreads();
#pragma unroll
    for (int j = 0; j < PW; ++j) {
      int t = wave * PW + j;
      if (t < ACALLS) {
        int lin = t * 64 + lane;
        int r = lin >> 2, c = lin & 3;         // 4 x 16B chunks per 32-elem row
        async16(A + (size_t)(m0 + r) * K + k0 + c * 8, lsA + t * 512);
      } else {
        int tb = t - ACALLS;
        int lin = tb * 64 + lane;
        int r = lin >> 2, c = lin & 3;
        async16(Bw + (size_t)(n0 + r) * K + k0 + c * 8, lsB + tb * 512);
      }
    }
    __syncthreads();
    s16x8 af[IT], bfr[4];
#pragma unroll
    for (int i = 0; i < IT; ++i)
      af[i] = *(const s16x8*)(lsA + (wm * (IT * 16) + i * 16 + l15) * 32 + q4 * 8);
#pragma unroll
    for (int j = 0; j < 4; ++j)
      bfr[j] = *(const s16x8*)(lsB + (wn * 64 + j * 16 + l15) * 32 + q4 * 8);
#pragma unroll
    for (int i = 0; i < IT; ++i)
#pragma unroll
      for (int j = 0; j < 4; ++j)
        acc[i][j] = __builtin_amdgcn_mfma_f32_16x16x32_bf16(af[i], bfr[j], acc[i][j], 0, 0, 0);
  }

  // epilogue: C/D layout col=lane&15, row=quad*4+reg
#pragma unroll
  for (int i = 0; i < IT; i++) {
#pragma unroll
    for (int j = 0; j < 4; j++) {
      int n = n0 + wn * 64 + j * 16 + l15;
      int mb = m0 + wm * (IT * 16) + i * 16 + q4 * 4;
      if (FINAL) {
#pragma unroll
        for (int r = 0; r < 4; r++)
          outp[(size_t)(mb + r) * DIM + n] = acc[i][j][r] + bias[n];
      } else if (n < 2048) {
#pragma unroll
        for (int r = 0; r < 4; r++)
          qkv[(size_t)(mb + r) * QKVN + n] = f2bf(acc[i][j][r]);
      } else {
        int b = mb >> 11, tok = mb & 2047;
        int h = (n >> 6) & 15, hd = n & 63;
        ushort4 pk;
        pk.x = f2bf(acc[i][j][0]); pk.y = f2bf(acc[i][j][1]);
        pk.z = f2bf(acc[i][j][2]); pk.w = f2bf(acc[i][j][3]);
        *(ushort4*)(vt + ((size_t)((b * NHEADS + h) * HD + hd)) * NSEQ + tok) = pk;
      }
    }
  }
}

// ---------------------------------------------------------------- flash attention
// LDS-traffic-minimized: S^T = K*Q^T (swapped operands). S^T's C-layout
// ([key=q4*4+r][qrow=l15]) IS the A-frag layout of mfma_16x16x16_bf16, so
// P = exp2(S^T) stays in registers (no LDS round-trip) and PV uses K=16 MFMAs
// with V B-frags as ds_read_b64 from vt. Per wave per 64-key tile: 8 ds_read_b128
// + 16 ds_read_b64, 0 ds_writes (was 36 b128 + 32 writes). 512 blocks
// (bh-major for XCD/L2 locality), 4 waves x 32 q-rows, double-buffered staging.
__global__ __launch_bounds__(256, 2) void attn_kernel(const u16* __restrict__ qkv,
                                                      const u16* __restrict__ vt,
                                                      u16* __restrict__ aout) {
  const int blk = blockIdx.x;            // 512 = 16 qtiles * 32 bh (bh fast)
  const int bh = blk & 31, qt = blk >> 5;
  const int b = bh >> 4, h = bh & 15;
  const int tid = threadIdx.x;
  const int wave = tid >> 6, lane = tid & 63;
  const int q4 = lane >> 4, l15 = lane & 15;

  __shared__ alignas(16) u16 lsK[2][64 * 64];    // [buf][key][hd], swizzled 16B chunks
  __shared__ alignas(16) u16 lsV[2][64 * 64];    // [buf][hd][key], swizzled 16B chunks

  // Q frags (B-operand of S^T MFMA), pre-scaled by log2(e)/8
  const float QSCALE = 0.18033688011112042f;     // log2(e)/8
  s16x8 aq[2][2];
#pragma unroll
  for (int rt = 0; rt < 2; ++rt)
#pragma unroll
    for (int kc = 0; kc < 2; ++kc) {
      int row = b * NSEQ + qt * 128 + wave * 32 + rt * 16 + l15;
      uint4 d = *(const uint4*)(qkv + (size_t)row * QKVN + h * HD + kc * 32 + q4 * 8);
      u32 w[4] = {d.x, d.y, d.z, d.w};
      s16x8 f;
#pragma unroll
      for (int j = 0; j < 8; ++j) {
        u16 u = (u16)(w[j >> 1] >> ((j & 1) * 16));
        float v = __uint_as_float(((u32)u) << 16) * QSCALE;
        f[j] = (short)f2bf(v);
      }
      aq[rt][kc] = f;
    }

  f32x4 o[2][4];
  float lsum[2] = {0.f, 0.f};                    // per-lane: qrow = l15
#pragma unroll
  for (int rt = 0; rt < 2; ++rt)
#pragma unroll
    for (int ht = 0; ht < 4; ++ht) o[rt][ht] = (f32x4){0.f, 0.f, 0.f, 0.f};

  auto stage = [&](int kt, int buf) {
#pragma unroll
    for (int j = 0; j < 2; ++j) {
      int t = wave * 2 + j;                      // 0..7
      int lin = t * 64 + lane;
      int r = lin >> 3, c = (lin & 7) ^ (r & 7);
      async16(qkv + (size_t)(b * NSEQ + kt * 64 + r) * QKVN + DIM + h * HD + c * 8,
              lsK[buf] + t * 512);
      async16(vt + (size_t)(bh * HD + r) * NSEQ + kt * 64 + c * 8,
              lsV[buf] + t * 512);
    }
  };

  stage(0, 0);

  for (int kt = 0; kt < 32; ++kt) {
    const int buf = kt & 1;
    __syncthreads();                             // stage(kt) complete; prev compute done
    if (kt + 1 < 32) stage(kt + 1, buf ^ 1);     // async into other buffer

    // hoisted fragment loads (shared by both rt groups)
    s16x8 kf[2][4];                              // [kc][ct]: A-frag K[key][hd]
#pragma unroll
    for (int kc = 0; kc < 2; ++kc)
#pragma unroll
      for (int ct = 0; ct < 4; ++ct) {
        int r = ct * 16 + l15;
        int c = (kc * 4 + q4) ^ (r & 7);
        kf[kc][ct] = *(const s16x8*)(lsK[buf] + r * 64 + c * 8);
      }
    s16x4 vf[4][4];                              // [ct(key chunk)][ht]: B-frag V[key][hd]
#pragma unroll
    for (int ct = 0; ct < 4; ++ct)
#pragma unroll
      for (int ht = 0; ht < 4; ++ht) {
        int row = ht * 16 + l15;                 // hd row in lsV
        int g = ct * 2 + (q4 >> 1);              // global 16B chunk (8 keys)
        int p = g ^ (row & 7);                   // swizzled position
        vf[ct][ht] = *(const s16x4*)(lsV[buf] + row * 64 + p * 8 + (q4 & 1) * 4);
      }

#pragma unroll
    for (int rt = 0; rt < 2; ++rt) {
      // S^T = K * Q^T : per ct, 16 keys x 16 qrows
      f32x4 st[4];
#pragma unroll
      for (int ct = 0; ct < 4; ++ct) st[ct] = (f32x4){0.f, 0.f, 0.f, 0.f};
#pragma unroll
      for (int kc = 0; kc < 2; ++kc)
#pragma unroll
        for (int ct = 0; ct < 4; ++ct)
          st[ct] = __builtin_amdgcn_mfma_f32_16x16x32_bf16(kf[kc][ct], aq[rt][kc], st[ct], 0, 0, 0);

      // P = exp2(S^T), truncated to bf16 in-register (A-frag of 16x16x16),
      // lsum accumulates the truncated values (normalizer == MFMA input)
      s16x4 pa[4];
#pragma unroll
      for (int ct = 0; ct < 4; ++ct) {
        u32 u0 = __float_as_uint(vexp2(st[ct][0]));
        u32 u1 = __float_as_uint(vexp2(st[ct][1]));
        u32 u2 = __float_as_uint(vexp2(st[ct][2]));
        u32 u3 = __float_as_uint(vexp2(st[ct][3]));
        lsum[rt] += __uint_as_float(u0 & 0xffff0000u) + __uint_as_float(u1 & 0xffff0000u) +
                    __uint_as_float(u2 & 0xffff0000u) + __uint_as_float(u3 & 0xffff0000u);
        union { u32 w[2]; s16x4 v; } pk;
        pk.w[0] = (u0 >> 16) | (u1 & 0xffff0000u);
        pk.w[1] = (u2 >> 16) | (u3 & 0xffff0000u);
        pa[ct] = pk.v;
      }

      // O += P * V  (16x16x16, K=16 per key-chunk ct)
#pragma unroll
      for (int ct = 0; ct < 4; ++ct)
#pragma unroll
        for (int ht = 0; ht < 4; ++ht)
          o[rt][ht] = __builtin_amdgcn_mfma_f32_16x16x16bf16_1k(pa[ct], vf[ct][ht], o[rt][ht], 0, 0, 0);
    }
  }

  // reduce lsum across the 4 q4 replicas (lanes l15 hold qrow sums)
#pragma unroll
  for (int rt = 0; rt < 2; ++rt) {
    lsum[rt] += __shfl_xor(lsum[rt], 16, 64);
    lsum[rt] += __shfl_xor(lsum[rt], 32, 64);
  }

#pragma unroll
  for (int rt = 0; rt < 2; ++rt) {
    float inv[4];
#pragma unroll
    for (int r = 0; r < 4; ++r) inv[r] = 1.0f / __shfl(lsum[rt], q4 * 4 + r, 64);
#pragma unroll
    for (int ht = 0; ht < 4; ++ht)
#pragma unroll
      for (int r = 0; r < 4; ++r) {
        int n = qt * 128 + wave * 32 + rt * 16 + q4 * 4 + r;
        int col = h * HD + ht * 16 + l15;
        aout[(size_t)(b * NSEQ + n) * DIM + col] = f2bf(o[rt][ht][r] * inv[r]);
      }
  }
}

// ---------------------------------------------------------------- launch
extern "C" void kernel_launch(void* const* d_in, const int* in_sizes, int n_in,
                              void* d_out, int out_size, void* d_ws, size_t ws_size,
                              hipStream_t stream) {
  const float* x     = (const float*)d_in[0];
  const float* w_qkv = (const float*)d_in[1];
  const float* w_prj = (const float*)d_in[2];
  const float* b_prj = (const float*)d_in[3];
  float* out = (float*)d_out;

  char* ws = (char*)d_ws;
  u16* x_bf    = (u16*)(ws);                          // 8 MB
  u16* wqkv_bf = (u16*)(ws + (size_t)(8u << 20));     // 6 MB
  u16* wprj_bf = (u16*)(ws + (size_t)(14u << 20));    // 2 MB
  u16* qkv     = (u16*)(ws + (size_t)(16u << 20));    // 24 MB (Q,K used; V slot unused)
  u16* vt      = (u16*)(ws + (size_t)(40u << 20));    // 8 MB
  u16* aout    = (u16*)(ws + (size_t)(48u << 20));    // 8 MB   total 56 MB

  cast_all<<<8192, 256, 0, stream>>>(x, w_qkv, w_prj, x_bf, wqkv_bf, wprj_bf);
  gemm_bt<false><<<32 * 24, 256, 0, stream>>>(x_bf, wqkv_bf, qkv, vt, nullptr, nullptr);
  attn_kernel<<<512, 256, 0, stream>>>(qkv, vt, aout);
  gemm_bt<true><<<64 * 8, 256, 0, stream>>>(aout, wprj_bf, nullptr, nullptr, b_prj, out);
}

// Round 10
// 180.189 us; speedup vs baseline: 1.0510x; 1.0433x over previous
//
#include <hip/hip_runtime.h>

typedef unsigned short u16;
typedef unsigned int u32;
typedef __attribute__((ext_vector_type(8))) short s16x8;   // 8 bf16 (4 VGPRs) MFMA A/B frag
typedef __attribute__((ext_vector_type(4))) short s16x4;   // 4 bf16 (2 VGPRs) 16x16x16 frag
typedef __attribute__((ext_vector_type(4))) float f32x4;   // MFMA C/D frag

#define DIM    1024
#define NHEADS 16
#define HD     64
#define NSEQ   2048
#define QKVN   3072

__device__ __forceinline__ u16 f2bf(float f) {
  u32 u = __float_as_uint(f);
  u += 0x7FFF + ((u >> 16) & 1);   // RNE
  return (u16)(u >> 16);
}

// exp2 via the compiler-visible intrinsic (single v_exp_f32 WITH hazard padding).
// r8/r9 used asm volatile("v_exp_f32") — LLVM's hazard recognizer does not pad
// TRANS-result hazards inside inline asm; schedule-dependent corruption.
__device__ __forceinline__ float vexp2(float x) {
#if __has_builtin(__builtin_amdgcn_exp2f)
  return __builtin_amdgcn_exp2f(x);
#else
  return __expf(x * 0.69314718055994531f);   // exp(x*ln2) == exp2(x), 2 VALU ops
#endif
}

// async global->LDS, 16B per lane. LDS dst = wave-uniform base + lane*16.
__device__ __forceinline__ void async16(const u16* g, u16* l) {
  __builtin_amdgcn_global_load_lds(
      (const __attribute__((address_space(1))) unsigned int*)g,
      (__attribute__((address_space(3))) unsigned int*)l, 16, 0, 0);
}

// ---------------------------------------------------------------- cast fp32 -> bf16
__global__ void cast_all(const float* __restrict__ x, const float* __restrict__ wq,
                         const float* __restrict__ wp, u16* __restrict__ xo,
                         u16* __restrict__ wqo, u16* __restrict__ wpo) {
  int i = blockIdx.x * 256 + threadIdx.x;        // 2,097,152 threads, 4 floats each
  const float4* src; u16* dst; int off;
  if (i < 1048576)      { src = (const float4*)x;  dst = xo;  off = i; }
  else if (i < 1835008) { src = (const float4*)wq; dst = wqo; off = i - 1048576; }
  else                  { src = (const float4*)wp; dst = wpo; off = i - 1835008; }
  float4 f = src[off];
  ushort4 o;
  o.x = f2bf(f.x); o.y = f2bf(f.y); o.z = f2bf(f.z); o.w = f2bf(f.w);
  ((ushort4*)dst)[off] = o;
}

// ---------------------------------------------------------------- GEMM  C = A * B^T
// m97-exact config: BK=32, LDS row stride 32 elems, async16 staging, 256 thr.
// FINAL=false: BM=128, grid 32x24; scalar coalesced Q,K stores -> qkv,
//              packed ushort4 V stores -> vt. FINAL=true: BM=64; out = C + bias.
template <bool FINAL>
__global__ __launch_bounds__(256, 3) void gemm_bt(
    const u16* __restrict__ A, const u16* __restrict__ Bw, u16* __restrict__ qkv,
    u16* __restrict__ vt, const float* __restrict__ bias, float* __restrict__ outp) {
  constexpr int K = 1024;
  constexpr int BM = FINAL ? 64 : 128;
  constexpr int MT = FINAL ? 64 : 32;
  constexpr int IT = FINAL ? 2 : 4;           // 16-row i-tiles per wave
  constexpr int ACALLS = BM / 16;             // wave-calls to stage A tile (1 KB each)
  constexpr int TCALLS = ACALLS + 8;
  constexpr int PW = TCALLS / 4;              // calls per wave
  const int bm = blockIdx.x % MT;
  const int bn = blockIdx.x / MT;
  const int tid = threadIdx.x;
  const int wave = tid >> 6, lane = tid & 63;
  const int q4 = lane >> 4, l15 = lane & 15;
  const int wm = wave >> 1, wn = wave & 1;
  const int m0 = bm * BM, n0 = bn * 128;

  __shared__ alignas(16) u16 lsA[BM * 32];
  __shared__ alignas(16) u16 lsB[128 * 32];

  f32x4 acc[IT][4];
#pragma unroll
  for (int i = 0; i < IT; i++)
#pragma unroll
    for (int j = 0; j < 4; j++) acc[i][j] = (f32x4){0.f, 0.f, 0.f, 0.f};

  for (int k0 = 0; k0 < K; k0 += 32) {
    __syncthreads();
#pragma unroll
    for (int j = 0; j < PW; ++j) {
      int t = wave * PW + j;
      if (t < ACALLS) {
        int lin = t * 64 + lane;
        int r = lin >> 2, c = lin & 3;         // 4 x 16B chunks per 32-elem row
        async16(A + (size_t)(m0 + r) * K + k0 + c * 8, lsA + t * 512);
      } else {
        int tb = t - ACALLS;
        int lin = tb * 64 + lane;
        int r = lin >> 2, c = lin & 3;
        async16(Bw + (size_t)(n0 + r) * K + k0 + c * 8, lsB + tb * 512);
      }
    }
    __syncthreads();
    s16x8 af[IT], bfr[4];
#pragma unroll
    for (int i = 0; i < IT; ++i)
      af[i] = *(const s16x8*)(lsA + (wm * (IT * 16) + i * 16 + l15) * 32 + q4 * 8);
#pragma unroll
    for (int j = 0; j < 4; ++j)
      bfr[j] = *(const s16x8*)(lsB + (wn * 64 + j * 16 + l15) * 32 + q4 * 8);
#pragma unroll
    for (int i = 0; i < IT; ++i)
#pragma unroll
      for (int j = 0; j < 4; ++j)
        acc[i][j] = __builtin_amdgcn_mfma_f32_16x16x32_bf16(af[i], bfr[j], acc[i][j], 0, 0, 0);
  }

  // epilogue: C/D layout col=lane&15, row=quad*4+reg
#pragma unroll
  for (int i = 0; i < IT; i++) {
#pragma unroll
    for (int j = 0; j < 4; j++) {
      int n = n0 + wn * 64 + j * 16 + l15;
      int mb = m0 + wm * (IT * 16) + i * 16 + q4 * 4;
      if (FINAL) {
#pragma unroll
        for (int r = 0; r < 4; r++)
          outp[(size_t)(mb + r) * DIM + n] = acc[i][j][r] + bias[n];
      } else if (n < 2048) {
#pragma unroll
        for (int r = 0; r < 4; r++)
          qkv[(size_t)(mb + r) * QKVN + n] = f2bf(acc[i][j][r]);
      } else {
        int b = mb >> 11, tok = mb & 2047;
        int h = (n >> 6) & 15, hd = n & 63;
        ushort4 pk;
        pk.x = f2bf(acc[i][j][0]); pk.y = f2bf(acc[i][j][1]);
        pk.z = f2bf(acc[i][j][2]); pk.w = f2bf(acc[i][j][3]);
        *(ushort4*)(vt + ((size_t)((b * NHEADS + h) * HD + hd)) * NSEQ + tok) = pk;
      }
    }
  }
}

// ---------------------------------------------------------------- flash attention
// In-block split-K (r9 structure, hazard-safe exp2): 4 waves = 2 key-groups x
// 2 q-waves; each wave 64 q-rows (rt=4) x 1024 keys (16 tiles). Single explicit
// 64 KB smem buffer: K dbuf pairs at [0,32KB), V dbuf pairs at [32KB,64KB);
// fp32 combine overlay (O 64x132 + lsum 128 = 34304 B) hand-placed at base.
// Fixed-shift softmax partials are additive: group 1 publishes O/lsum to the
// overlay, group 0 combines+normalizes+stores. S^T = K*Q^T keeps P in
// registers (C-layout == 16x16x16 A-frag layout).
__global__ __launch_bounds__(256, 2) void attn_kernel(const u16* __restrict__ qkv,
                                                      const u16* __restrict__ vt,
                                                      u16* __restrict__ aout) {
  const int blk = blockIdx.x;            // 512 = 16 qtiles * 32 bh (bh fast)
  const int bh = blk & 31, qt = blk >> 5;
  const int b = bh >> 4, h = bh & 15;
  const int tid = threadIdx.x;
  const int wave = tid >> 6, lane = tid & 63;
  const int g = wave >> 1, wq = wave & 1;      // key-group, q-position
  const int q4 = lane >> 4, l15 = lane & 15;

  __shared__ alignas(16) u16 smem[32768];      // 64 KB, hand-partitioned
  u16* lsKb = smem + g * 2 * 4096;             // this group's two K buffers
  u16* lsVb = smem + 16384 + g * 2 * 4096;     // this group's two V buffers
  float* lsO = (float*)smem;                   // combine overlay: 64 cols x stride 132
  float* lsS = lsO + 64 * 132;                 // + 128 row-sums (total 34304 B < 64 KB)

  // Q frags (B-operand of S^T MFMA), pre-scaled by log2(e)/8
  const float QSCALE = 0.18033688011112042f;       // log2(e)/8
  s16x8 aq[4][2];
#pragma unroll
  for (int rt = 0; rt < 4; ++rt)
#pragma unroll
    for (int kc = 0; kc < 2; ++kc) {
      int row = b * NSEQ + qt * 128 + wq * 64 + rt * 16 + l15;
      uint4 d = *(const uint4*)(qkv + (size_t)row * QKVN + h * HD + kc * 32 + q4 * 8);
      u32 w[4] = {d.x, d.y, d.z, d.w};
      s16x8 f;
#pragma unroll
      for (int j = 0; j < 8; ++j) {
        u16 u = (u16)(w[j >> 1] >> ((j & 1) * 16));
        float v = __uint_as_float(((u32)u) << 16) * QSCALE;
        f[j] = (short)f2bf(v);
      }
      aq[rt][kc] = f;
    }

  f32x4 o[4][4];
  float lsum[4] = {0.f, 0.f, 0.f, 0.f};            // per-lane: qrow = l15 (per rt)
#pragma unroll
  for (int rt = 0; rt < 4; ++rt)
#pragma unroll
    for (int ht = 0; ht < 4; ++ht) o[rt][ht] = (f32x4){0.f, 0.f, 0.f, 0.f};

  // stage tile ktl of this group's key-half into buffer buf (8 K + 8 V calls / 2 waves)
  auto stage = [&](int ktl, int buf) {
#pragma unroll
    for (int j = 0; j < 4; ++j) {
      int t = wq * 4 + j;                          // 0..7
      int lin = t * 64 + lane;
      int r = lin >> 3, c = (lin & 7) ^ (r & 7);
      int key = g * 1024 + ktl * 64;
      async16(qkv + (size_t)(b * NSEQ + key + r) * QKVN + DIM + h * HD + c * 8,
              lsKb + buf * 4096 + t * 512);
      async16(vt + (size_t)(bh * HD + r) * NSEQ + key + c * 8,
              lsVb + buf * 4096 + t * 512);
    }
  };

  stage(0, 0);

  for (int kt = 0; kt < 16; ++kt) {
    const int buf = kt & 1;
    __syncthreads();                               // stage(kt) complete; prev compute done
    if (kt + 1 < 16) stage(kt + 1, buf ^ 1);       // async into other buffer
    const u16* lsK = lsKb + buf * 4096;
    const u16* lsV = lsVb + buf * 4096;

    // hoisted fragment loads (shared by all 4 rt chains)
    s16x8 kf[2][4];                                // [kc][ct]: A-frag K[key][hd]
#pragma unroll
    for (int kc = 0; kc < 2; ++kc)
#pragma unroll
      for (int ct = 0; ct < 4; ++ct) {
        int r = ct * 16 + l15;
        int c = (kc * 4 + q4) ^ (r & 7);
        kf[kc][ct] = *(const s16x8*)(lsK + r * 64 + c * 8);
      }
    s16x4 vf[4][4];                                // [ct(key chunk)][ht]: B-frag V[key][hd]
#pragma unroll
    for (int ct = 0; ct < 4; ++ct)
#pragma unroll
      for (int ht = 0; ht < 4; ++ht) {
        int row = ht * 16 + l15;                   // hd row in lsV
        int gch = ct * 2 + (q4 >> 1);              // global 16B chunk (8 keys)
        int p = gch ^ (row & 7);                   // swizzled position
        vf[ct][ht] = *(const s16x4*)(lsV + row * 64 + p * 8 + (q4 & 1) * 4);
      }

#pragma unroll
    for (int rt = 0; rt < 4; ++rt) {
      // S^T = K * Q^T : per ct, 16 keys x 16 qrows
      f32x4 st[4];
#pragma unroll
      for (int ct = 0; ct < 4; ++ct) st[ct] = (f32x4){0.f, 0.f, 0.f, 0.f};
#pragma unroll
      for (int kc = 0; kc < 2; ++kc)
#pragma unroll
        for (int ct = 0; ct < 4; ++ct)
          st[ct] = __builtin_amdgcn_mfma_f32_16x16x32_bf16(kf[kc][ct], aq[rt][kc], st[ct], 0, 0, 0);

      // P = exp2(S^T), truncated to bf16 in-register (A-frag of 16x16x16);
      // lsum accumulates the truncated values (normalizer == MFMA input)
      s16x4 pa[4];
#pragma unroll
      for (int ct = 0; ct < 4; ++ct) {
        u32 u0 = __float_as_uint(vexp2(st[ct][0]));
        u32 u1 = __float_as_uint(vexp2(st[ct][1]));
        u32 u2 = __float_as_uint(vexp2(st[ct][2]));
        u32 u3 = __float_as_uint(vexp2(st[ct][3]));
        lsum[rt] += __uint_as_float(u0 & 0xffff0000u) + __uint_as_float(u1 & 0xffff0000u) +
                    __uint_as_float(u2 & 0xffff0000u) + __uint_as_float(u3 & 0xffff0000u);
        union { u32 w[2]; s16x4 v; } pk;
        pk.w[0] = (u0 >> 16) | (u1 & 0xffff0000u);
        pk.w[1] = (u2 >> 16) | (u3 & 0xffff0000u);
        pa[ct] = pk.v;
      }

      // O += P * V  (16x16x16, K=16 per key-chunk ct)
#pragma unroll
      for (int ct = 0; ct < 4; ++ct)
#pragma unroll
        for (int ht = 0; ht < 4; ++ht)
          o[rt][ht] = __builtin_amdgcn_mfma_f32_16x16x16bf16_1k(pa[ct], vf[ct][ht], o[rt][ht], 0, 0, 0);
    }
  }

  // reduce lsum across the 4 q4 replicas (every lane then holds qrow=l15's sum)
#pragma unroll
  for (int rt = 0; rt < 4; ++rt) {
    lsum[rt] += __shfl_xor(lsum[rt], 16, 64);
    lsum[rt] += __shfl_xor(lsum[rt], 32, 64);
  }

  __syncthreads();                                 // all staging reads done; overlay LDS
  if (g == 1) {
    // publish group-1 partials: O fp32 (col-major, stride 132, b128) + lsums
#pragma unroll
    for (int rt = 0; rt < 4; ++rt) {
#pragma unroll
      for (int ht = 0; ht < 4; ++ht) {
        int addr = (ht * 16 + l15) * 132 + wq * 64 + rt * 16 + q4 * 4;
        *(float4*)(lsO + addr) = (float4){o[rt][ht][0], o[rt][ht][1], o[rt][ht][2], o[rt][ht][3]};
      }
      if (q4 == 0) lsS[wq * 64 + rt * 16 + l15] = lsum[rt];
    }
  }
  __syncthreads();
  if (g == 0) {
#pragma unroll
    for (int rt = 0; rt < 4; ++rt) {
      float4 s2 = *(const float4*)(lsS + wq * 64 + rt * 16 + q4 * 4);  // broadcast
      float inv[4];
      inv[0] = 1.0f / (__shfl(lsum[rt], q4 * 4 + 0, 64) + s2.x);
      inv[1] = 1.0f / (__shfl(lsum[rt], q4 * 4 + 1, 64) + s2.y);
      inv[2] = 1.0f / (__shfl(lsum[rt], q4 * 4 + 2, 64) + s2.z);
      inv[3] = 1.0f / (__shfl(lsum[rt], q4 * 4 + 3, 64) + s2.w);
#pragma unroll
      for (int ht = 0; ht < 4; ++ht) {
        float4 o2 = *(const float4*)(lsO + (ht * 16 + l15) * 132 + wq * 64 + rt * 16 + q4 * 4);
        float v[4] = {o[rt][ht][0] + o2.x, o[rt][ht][1] + o2.y,
                      o[rt][ht][2] + o2.z, o[rt][ht][3] + o2.w};
#pragma unroll
        for (int r = 0; r < 4; ++r) {
          int n = qt * 128 + wq * 64 + rt * 16 + q4 * 4 + r;
          int col = h * HD + ht * 16 + l15;
          aout[(size_t)(b * NSEQ + n) * DIM + col] = f2bf(v[r] * inv[r]);
        }
      }
    }
  }
}

// ---------------------------------------------------------------- launch
extern "C" void kernel_launch(void* const* d_in, const int* in_sizes, int n_in,
                              void* d_out, int out_size, void* d_ws, size_t ws_size,
                              hipStream_t stream) {
  const float* x     = (const float*)d_in[0];
  const float* w_qkv = (const float*)d_in[1];
  const float* w_prj = (const float*)d_in[2];
  const float* b_prj = (const float*)d_in[3];
  float* out = (float*)d_out;

  char* ws = (char*)d_ws;
  u16* x_bf    = (u16*)(ws);                          // 8 MB
  u16* wqkv_bf = (u16*)(ws + (size_t)(8u << 20));     // 6 MB
  u16* wprj_bf = (u16*)(ws + (size_t)(14u << 20));    // 2 MB
  u16* qkv     = (u16*)(ws + (size_t)(16u << 20));    // 24 MB (Q,K used; V slot unused)
  u16* vt      = (u16*)(ws + (size_t)(40u << 20));    // 8 MB
  u16* aout    = (u16*)(ws + (size_t)(48u << 20));    // 8 MB   total 56 MB

  cast_all<<<8192, 256, 0, stream>>>(x, w_qkv, w_prj, x_bf, wqkv_bf, wprj_bf);
  gemm_bt<false><<<32 * 24, 256, 0, stream>>>(x_bf, wqkv_bf, qkv, vt, nullptr, nullptr);
  attn_kernel<<<512, 256, 0, stream>>>(qkv, vt, aout);
  gemm_bt<true><<<64 * 8, 256, 0, stream>>>(aout, wprj_bf, nullptr, nullptr, b_prj, out);
}